// Round 8
// baseline (310.353 us; speedup 1.0000x reference)
//
#include <hip/hip_runtime.h>

#define Tt 1024
#define Dh 64

typedef __attribute__((ext_vector_type(4))) float f32x4;
typedef __attribute__((ext_vector_type(8))) short bf16x8;
typedef __attribute__((ext_vector_type(8))) unsigned short u16x8;

__device__ inline unsigned short f2bf(float x){
  __bf16 h = (__bf16)x;                      // RNE, same as manual round
  return __builtin_bit_cast(unsigned short, h);
}
__device__ inline float bf2f(unsigned short h){
  return __uint_as_float(((unsigned)h) << 16);
}
__device__ inline ushort4 pack4(float4 f){
  ushort4 u; u.x=f2bf(f.x); u.y=f2bf(f.y); u.z=f2bf(f.z); u.w=f2bf(f.w); return u;
}
__device__ inline bf16x8 pack8(float4 a, float4 b){
  bf16x8 r;
  r[0]=(short)f2bf(a.x); r[1]=(short)f2bf(a.y); r[2]=(short)f2bf(a.z); r[3]=(short)f2bf(a.w);
  r[4]=(short)f2bf(b.x); r[5]=(short)f2bf(b.y); r[6]=(short)f2bf(b.z); r[7]=(short)f2bf(b.w);
  return r;
}
__device__ inline f32x4 mfma16(bf16x8 a, bf16x8 b, f32x4 c){
  return __builtin_amdgcn_mfma_f32_16x16x32_bf16(a, b, c, 0, 0, 0);
}

// stage a [64][64] fp32 tile (row stride 64) -> bf16 LDS [64][68]
__device__ inline void stage64x64(const float* __restrict__ g, unsigned short (*lds)[68], int tid){
  int r = tid >> 2, c = (tid & 3) * 16;
  const float4* g4 = (const float4*)(g + (size_t)r * 64 + c);
  float4 f0 = g4[0], f1 = g4[1], f2_ = g4[2], f3 = g4[3];
  ushort4* d4 = (ushort4*)&lds[r][c];
  d4[0]=pack4(f0); d4[1]=pack4(f1); d4[2]=pack4(f2_); d4[3]=pack4(f3);
}
// stage a [64 k][64 d] fp32 tile TRANSPOSED -> lds[d][k] bf16, via 4x4 register-block transpose.
__device__ inline void stage64x64T4(const float* __restrict__ g, unsigned short (*lds)[68], int tid){
  const int kb = (tid >> 4) * 4, db = (tid & 15) * 4;
  float fv[4][4];
#pragma unroll
  for (int j = 0; j < 4; ++j){
    float4 f = *(const float4*)(g + (size_t)(kb + j) * 64 + db);
    fv[j][0]=f.x; fv[j][1]=f.y; fv[j][2]=f.z; fv[j][3]=f.w;
  }
#pragma unroll
  for (int i = 0; i < 4; ++i){
    ushort4 u;
    u.x=f2bf(fv[0][i]); u.y=f2bf(fv[1][i]); u.z=f2bf(fv[2][i]); u.w=f2bf(fv[3][i]);
    *(ushort4*)&lds[db + i][kb] = u;
  }
}
__device__ inline bf16x8 ldsfrag(const unsigned short (*lds)[68], int row, int col){
  const ushort4* p = (const ushort4*)&lds[row][col];
  ushort4 u0 = p[0], u1 = p[1];
  bf16x8 r;
  r[0]=(short)u0.x; r[1]=(short)u0.y; r[2]=(short)u0.z; r[3]=(short)u0.w;
  r[4]=(short)u1.x; r[5]=(short)u1.y; r[6]=(short)u1.z; r[7]=(short)u1.w;
  return r;
}
__device__ inline float fragsum(bf16x8 v){
  float s = 0.f;
#pragma unroll
  for (int i = 0; i < 8; ++i) s += bf2f((unsigned short)v[i]);
  return s;
}

// ---------------- Kernel 1: bias (pre-scaled by 1/8 via Q) in CONSUMER-FRAGMENT layout ----------------
// BIASF[bh][qt2][kt][tid][j*4+c], 2B elems. Grid swizzled: XCD x handles qi in [128x,128x+128)
// so the 4 consecutive qi sharing each 32B chunk write-combine in one XCD's L2.
__global__ __launch_bounds__(256) void k_qek(const float* __restrict__ Q,
                                             const float* __restrict__ EK,
                                             unsigned short* __restrict__ BIASF){
  __shared__ unsigned short ek[2][64][68];
  const int bid = blockIdx.x;
  const int qi = (bid >> 3) + 128 * (bid & 7);
  const int tid = threadIdx.x;
  const int w = tid >> 6, l = tid & 63, lr = l & 15, lg = l >> 4;

  bf16x8 a0, a1;   // A rows bh = 16w+lr, Q pre-scaled by 0.125 (exact in bf16)
  {
    const float4* q4 = (const float4*)(Q + ((size_t)(16*w + lr) * Tt + qi) * Dh);
    float4 qa=q4[lg*2], qb=q4[lg*2+1], qc=q4[8+lg*2], qd=q4[8+lg*2+1];
    qa.x*=0.125f; qa.y*=0.125f; qa.z*=0.125f; qa.w*=0.125f;
    qb.x*=0.125f; qb.y*=0.125f; qb.z*=0.125f; qb.w*=0.125f;
    qc.x*=0.125f; qc.y*=0.125f; qc.z*=0.125f; qc.w*=0.125f;
    qd.x*=0.125f; qd.y*=0.125f; qd.z*=0.125f; qd.w*=0.125f;
    a0 = pack8(qa, qb); a1 = pack8(qc, qd);
  }
  const float* ekq = EK + (size_t)qi * Tt * Dh;
  const int qt2 = qi >> 6, J = qi & 3;
  const int tid2 = ((qi >> 4) & 3) * 64 + ((qi >> 2) & 3) * 16 + lr;
  size_t sb[4];
#pragma unroll
  for (int j = 0; j < 4; ++j){
    int bh = 16*w + 4*lg + j;
    sb[j] = (size_t)(bh*16 + qt2) * 65536 + (size_t)tid2 * 16 + J * 4;
  }

  stage64x64(ekq, ek[0], tid);
  __syncthreads();

#pragma unroll 2
  for (int kt = 0; kt < 16; ++kt){
    if (kt < 15) stage64x64(ekq + (size_t)(kt+1)*64*Dh, ek[(kt+1)&1], tid);
    const unsigned short (*cur)[68] = ek[kt&1];
    f32x4 acc[4];
#pragma unroll
    for (int c = 0; c < 4; ++c){
      bf16x8 b0 = ldsfrag(cur, c*16 + lr, lg*8);
      bf16x8 b1 = ldsfrag(cur, c*16 + lr, lg*8 + 32);
      f32x4 z = {0.f,0.f,0.f,0.f};
      z = mfma16(a0, b0, z);
      z = mfma16(a1, b1, z);
      acc[c] = z;
    }
#pragma unroll
    for (int j = 0; j < 4; ++j){
      ushort4 u;
      u.x=f2bf(acc[0][j]); u.y=f2bf(acc[1][j]); u.z=f2bf(acc[2][j]); u.w=f2bf(acc[3][j]);
      *(ushort4*)(BIASF + sb[j] + (size_t)kt * 4096) = u;
    }
    __syncthreads();
  }
}

// ------- Kernel 2: P = exp(QK^T/8 + bias) -> P ws (unnormalized); OUT = (P*V)/rowsum(P).
//         Bias read as 32B register fragments (no LDS), prefetched 1 tile ahead.
//         K/V double-buffered LDS, ONE __syncthreads per tile. XCD swizzle for K/V L2 locality.
__global__ __launch_bounds__(256) void k_attn(const float* __restrict__ Q,
                                              const float* __restrict__ K,
                                              const float* __restrict__ V,
                                              const unsigned short* __restrict__ BIASF,
                                              unsigned short* __restrict__ P,
                                              float* __restrict__ OUT){
  __shared__ unsigned short ktile[2][64][68];
  __shared__ unsigned short vtile[2][64][68];
  __shared__ unsigned short pt[64][68];
  const int bid = blockIdx.x;
  const int bh = (bid & 7) + ((bid >> 7) << 3);   // bid = (bh&7) + 8*((bh>>3)*16 + qt2)
  const int qt2 = (bid >> 3) & 15;
  const int qt = qt2 * 64;
  const int tid = threadIdx.x;
  const int w = tid >> 6, l = tid & 63, lr = l & 15, lg = l >> 4;
  const int or_ = l >> 2, oc = (l & 3) * 16;

  bf16x8 a0, a1;   // A rows q = qt+16w+lr, Q pre-scaled by 0.125
  {
    const float4* q4 = (const float4*)(Q + ((size_t)bh * Tt + qt + 16*w + lr) * Dh);
    float4 qa=q4[lg*2], qb=q4[lg*2+1], qc=q4[8+lg*2], qd=q4[8+lg*2+1];
    qa.x*=0.125f; qa.y*=0.125f; qa.z*=0.125f; qa.w*=0.125f;
    qb.x*=0.125f; qb.y*=0.125f; qb.z*=0.125f; qb.w*=0.125f;
    qc.x*=0.125f; qc.y*=0.125f; qc.z*=0.125f; qc.w*=0.125f;
    qd.x*=0.125f; qd.y*=0.125f; qd.z*=0.125f; qd.w*=0.125f;
    a0 = pack8(qa, qb); a1 = pack8(qc, qd);
  }
  const float* kb = K + (size_t)bh * Tt * Dh;
  const float* vb = V + (size_t)bh * Tt * Dh;
  unsigned short* pb = P + (size_t)bh * Tt * Tt;
  const unsigned short* bbase = BIASF + (size_t)(bh*16 + qt2) * 65536 + (size_t)tid * 16;

  float lsum[4] = {0.f,0.f,0.f,0.f};
  f32x4 oacc[4];
#pragma unroll
  for (int c = 0; c < 4; ++c) oacc[c] = (f32x4){0.f,0.f,0.f,0.f};

  u16x8 bc0, bc1, bn0, bn1;
  stage64x64 (kb, ktile[0], tid);
  stage64x64T4(vb, vtile[0], tid);
  { const u16x8* bp = (const u16x8*)bbase; bc0 = bp[0]; bc1 = bp[1]; }
  __syncthreads();

#pragma unroll 2
  for (int kt = 0; kt < 16; ++kt){
    if (kt < 15){
      stage64x64 (kb + (size_t)(kt+1)*64*Dh, ktile[(kt+1)&1], tid);
      stage64x64T4(vb + (size_t)(kt+1)*64*Dh, vtile[(kt+1)&1], tid);
      const u16x8* bp = (const u16x8*)(bbase + (size_t)(kt+1) * 4096);
      bn0 = bp[0]; bn1 = bp[1];
    }
    const unsigned short (*kc)[68] = ktile[kt&1];
    const unsigned short (*vc)[68] = vtile[kt&1];
#pragma unroll
    for (int c = 0; c < 4; ++c){
      bf16x8 b0 = ldsfrag(kc, c*16 + lr, lg*8);
      bf16x8 b1 = ldsfrag(kc, c*16 + lr, lg*8 + 32);
      f32x4 z = {0.f,0.f,0.f,0.f};
      z = mfma16(a0, b0, z);
      z = mfma16(a1, b1, z);
      int kl = c*16 + lr;
#pragma unroll
      for (int j = 0; j < 4; ++j){
        const int idx = j*4 + c;
        float bv = bf2f(idx < 8 ? bc0[idx] : bc1[idx-8]);
        float p = __expf(z[j] + bv);
        lsum[j] += p;
        pt[16*w + lg*4 + j][kl] = f2bf(p);
      }
    }
    __builtin_amdgcn_wave_barrier();            // pt rows wave-local
    {
      const ushort4* s4 = (const ushort4*)&pt[16*w + or_][oc];
      ushort4 u0=s4[0], u1=s4[1], u2=s4[2], u3=s4[3];
      ushort4* d4 = (ushort4*)(pb + (size_t)(qt + 16*w + or_)*Tt + kt*64 + oc);
      d4[0]=u0; d4[1]=u1; d4[2]=u2; d4[3]=u3;
    }
    bf16x8 p0 = ldsfrag(pt, 16*w + lr, lg*8);
    bf16x8 p1 = ldsfrag(pt, 16*w + lr, lg*8 + 32);
#pragma unroll
    for (int c = 0; c < 4; ++c){
      bf16x8 v0 = ldsfrag(vc, c*16 + lr, lg*8);
      bf16x8 v1 = ldsfrag(vc, c*16 + lr, lg*8 + 32);
      oacc[c] = mfma16(p0, v0, oacc[c]);
      oacc[c] = mfma16(p1, v1, oacc[c]);
    }
    bc0 = bn0; bc1 = bn1;
    __syncthreads();
  }
  float rl[4];
#pragma unroll
  for (int j = 0; j < 4; ++j){
    float su = lsum[j];
    for (int o = 1; o < 16; o <<= 1) su += __shfl_xor(su, o, 64);
    rl[j] = 1.f / su;
  }
#pragma unroll
  for (int c = 0; c < 4; ++c)
#pragma unroll
    for (int j = 0; j < 4; ++j)
      OUT[((size_t)bh * Tt + qt + 16*w + lg*4 + j) * Dh + c*16 + lr] = oacc[c][j] * rl[j];
}

// ---------------- Kernel 3: OUT[bh,q,d] += (sum_k P*Ev)/rowsum(P) ---------------- (R6 version)
__global__ __launch_bounds__(256) void k_aev(const unsigned short* __restrict__ P,
                                             const float* __restrict__ EV,
                                             float* __restrict__ OUT){
  __shared__ unsigned short evt[2][64][68];
  __shared__ float sums[64];
  const int qi = blockIdx.x;
  const int tid = threadIdx.x;
  const int w = tid >> 6, l = tid & 63, lr = l & 15, lg = l >> 4;

  const unsigned short* arow = P + (size_t)(16*w + lr) * Tt * Tt + (size_t)qi * Tt;
  const float* evq = EV + (size_t)qi * Tt * Dh;

  f32x4 acc[4];
#pragma unroll
  for (int c = 0; c < 4; ++c) acc[c] = (f32x4){0.f,0.f,0.f,0.f};
  float asum = 0.f;

  stage64x64T4(evq, evt[0], tid);
  __syncthreads();

#pragma unroll 2
  for (int kt = 0; kt < 16; ++kt){
    if (kt < 15) stage64x64T4(evq + (size_t)(kt+1) * 64 * Dh, evt[(kt+1)&1], tid);
    const unsigned short (*cur)[68] = evt[kt&1];
    bf16x8 a0 = *(const bf16x8*)(arow + kt*64 + lg*8);
    bf16x8 a1 = *(const bf16x8*)(arow + kt*64 + 32 + lg*8);
    asum += fragsum(a0) + fragsum(a1);
#pragma unroll
    for (int c = 0; c < 4; ++c){
      bf16x8 b0 = ldsfrag(cur, c*16 + lr, lg*8);
      bf16x8 b1 = ldsfrag(cur, c*16 + lr, lg*8 + 32);
      acc[c] = mfma16(a0, b0, acc[c]);
      acc[c] = mfma16(a1, b1, acc[c]);
    }
    __syncthreads();
  }
  asum += __shfl_xor(asum, 16, 64);
  asum += __shfl_xor(asum, 32, 64);
  if (lg == 0) sums[16*w + lr] = asum;
  __builtin_amdgcn_wave_barrier();

#pragma unroll
  for (int c = 0; c < 4; ++c)
#pragma unroll
    for (int j = 0; j < 4; ++j){
      int bh = 16*w + lg*4 + j;
      float rl = 1.f / sums[bh];
      size_t idx = ((size_t)bh * Tt + qi) * Dh + c*16 + lr;
      OUT[idx] += acc[c][j] * rl;
    }
}

extern "C" void kernel_launch(void* const* d_in, const int* in_sizes, int n_in,
                              void* d_out, int out_size, void* d_ws, size_t ws_size,
                              hipStream_t stream){
  const float* Q  = (const float*)d_in[0];
  const float* K  = (const float*)d_in[1];
  const float* V  = (const float*)d_in[2];
  const float* EK = (const float*)d_in[3];
  const float* EV = (const float*)d_in[4];
  float* OUT = (float*)d_out;
  unsigned short* WSP = (unsigned short*)d_ws;                       // P: 128 MiB
  unsigned short* WS2 = WSP + (size_t)64 * Tt * Tt;                  // bias frags: 128 MiB

  if (ws_size < (size_t)2 * 64 * Tt * Tt * sizeof(unsigned short)) return;

  k_qek <<<dim3(1024), dim3(256), 0, stream>>>(Q, EK, WS2);
  k_attn<<<dim3(1024), dim3(256), 0, stream>>>(Q, K, V, WS2, WSP, OUT);
  k_aev <<<dim3(1024), dim3(256), 0, stream>>>(WSP, EV, OUT);
}

// Round 9
// 268.550 us; speedup vs baseline: 1.1557x; 1.1557x over previous
//
#include <hip/hip_runtime.h>

#define Tt 1024
#define Dh 64
#define SCALE 0.125f

typedef __attribute__((ext_vector_type(4))) float f32x4;
typedef __attribute__((ext_vector_type(8))) short bf16x8;

__device__ inline unsigned short f2bf(float x){
  __bf16 h = (__bf16)x;                      // native cvt, RNE — bit-identical to manual round
  return __builtin_bit_cast(unsigned short, h);
}
__device__ inline float bf2f(unsigned short h){
  return __uint_as_float(((unsigned)h) << 16);
}
__device__ inline ushort4 pack4(float4 f){
  ushort4 u; u.x=f2bf(f.x); u.y=f2bf(f.y); u.z=f2bf(f.z); u.w=f2bf(f.w); return u;
}
__device__ inline bf16x8 pack8(float4 a, float4 b){
  bf16x8 r;
  r[0]=(short)f2bf(a.x); r[1]=(short)f2bf(a.y); r[2]=(short)f2bf(a.z); r[3]=(short)f2bf(a.w);
  r[4]=(short)f2bf(b.x); r[5]=(short)f2bf(b.y); r[6]=(short)f2bf(b.z); r[7]=(short)f2bf(b.w);
  return r;
}
__device__ inline f32x4 mfma16(bf16x8 a, bf16x8 b, f32x4 c){
  return __builtin_amdgcn_mfma_f32_16x16x32_bf16(a, b, c, 0, 0, 0);
}

// stage a [64][64] fp32 tile (row stride 64) -> bf16 LDS [64][68]
__device__ inline void stage64x64(const float* __restrict__ g, unsigned short (*lds)[68], int tid){
  int r = tid >> 2, c = (tid & 3) * 16;
  const float4* g4 = (const float4*)(g + (size_t)r * 64 + c);
  float4 f0 = g4[0], f1 = g4[1], f2_ = g4[2], f3 = g4[3];
  ushort4* d4 = (ushort4*)&lds[r][c];
  d4[0]=pack4(f0); d4[1]=pack4(f1); d4[2]=pack4(f2_); d4[3]=pack4(f3);
}
// stage a [64 k][64 d] fp32 tile TRANSPOSED -> lds[d][k] bf16, via 4x4 register-block transpose.
__device__ inline void stage64x64T4(const float* __restrict__ g, unsigned short (*lds)[68], int tid){
  const int kb = (tid >> 4) * 4, db = (tid & 15) * 4;
  float fv[4][4];
#pragma unroll
  for (int j = 0; j < 4; ++j){
    float4 f = *(const float4*)(g + (size_t)(kb + j) * 64 + db);
    fv[j][0]=f.x; fv[j][1]=f.y; fv[j][2]=f.z; fv[j][3]=f.w;
  }
#pragma unroll
  for (int i = 0; i < 4; ++i){
    ushort4 u;
    u.x=f2bf(fv[0][i]); u.y=f2bf(fv[1][i]); u.z=f2bf(fv[2][i]); u.w=f2bf(fv[3][i]);
    *(ushort4*)&lds[db + i][kb] = u;
  }
}
// stage 64 rows x 64 ushorts from global (row stride in ushorts) -> LDS [64][68]
__device__ inline void stage_rows(const unsigned short* __restrict__ g, size_t rowstride,
                                  unsigned short (*lds)[68], int tid){
  int r = tid >> 2, c = (tid & 3) * 16;
  const ushort4* s4 = (const ushort4*)(g + (size_t)r * rowstride + c);
  ushort4 u0=s4[0], u1=s4[1], u2=s4[2], u3=s4[3];
  ushort4* d4 = (ushort4*)&lds[r][c];
  d4[0]=u0; d4[1]=u1; d4[2]=u2; d4[3]=u3;
}
// read 8 consecutive bf16 from lds[row][col..col+7] (col multiple of 8)
__device__ inline bf16x8 ldsfrag(const unsigned short (*lds)[68], int row, int col){
  const ushort4* p = (const ushort4*)&lds[row][col];
  ushort4 u0 = p[0], u1 = p[1];
  bf16x8 r;
  r[0]=(short)u0.x; r[1]=(short)u0.y; r[2]=(short)u0.z; r[3]=(short)u0.w;
  r[4]=(short)u1.x; r[5]=(short)u1.y; r[6]=(short)u1.z; r[7]=(short)u1.w;
  return r;
}
__device__ inline float fragsum(bf16x8 v){
  float s = 0.f;
#pragma unroll
  for (int i = 0; i < 8; ++i) s += bf2f((unsigned short)v[i]);
  return s;
}

// ---------------- Kernel 1: bias[bh][q][k] = sum_d Q[bh,q,d] * Ek[q,k,d]  (bf16 out) ----------------
// Double-buffered EK staging: one __syncthreads per kt; ot bounce is wave-local (wave_barrier only).
__global__ __launch_bounds__(256) void k_qek(const float* __restrict__ Q,
                                             const float* __restrict__ EK,
                                             unsigned short* __restrict__ BIAS){
  __shared__ unsigned short ek[2][64][68];
  __shared__ unsigned short ot[4][16][68];
  const int qi = blockIdx.x;
  const int tid = threadIdx.x;
  const int w = tid >> 6, l = tid & 63, lr = l & 15, lg = l >> 4;

  bf16x8 a0, a1;   // A rows bh = 16w+lr, k-dim d = lg*8+i (+32)
  {
    const float4* q4 = (const float4*)(Q + ((size_t)(16*w + lr) * Tt + qi) * Dh);
    a0 = pack8(q4[lg*2],     q4[lg*2 + 1]);
    a1 = pack8(q4[8 + lg*2], q4[8 + lg*2 + 1]);
  }
  const float* ekq = EK + (size_t)qi * Tt * Dh;
  const int r = l >> 2, c2 = (l & 3) * 16;
  unsigned short* dst0 = BIAS + (size_t)(16*w + r) * Tt * Tt + (size_t)qi * Tt + c2;

  stage64x64(ekq, ek[0], tid);
  __syncthreads();

  for (int kt = 0; kt < 16; ++kt){
    if (kt < 15) stage64x64(ekq + (size_t)(kt+1) * 64 * Dh, ek[(kt+1)&1], tid);
    const unsigned short (*cur)[68] = ek[kt&1];
    f32x4 acc[4];
#pragma unroll
    for (int c = 0; c < 4; ++c){
      bf16x8 b0 = ldsfrag(cur, c*16 + lr, lg*8);
      bf16x8 b1 = ldsfrag(cur, c*16 + lr, lg*8 + 32);
      f32x4 z = {0.f,0.f,0.f,0.f};
      z = mfma16(a0, b0, z);
      z = mfma16(a1, b1, z);
      acc[c] = z;
    }
#pragma unroll
    for (int c = 0; c < 4; ++c)
#pragma unroll
      for (int j = 0; j < 4; ++j)
        ot[w][lg*4 + j][c*16 + lr] = f2bf(acc[c][j]);
    __builtin_amdgcn_wave_barrier();   // wave-local bounce: rows [16w,16w+16) only
    {
      const ushort4* s4 = (const ushort4*)&ot[w][r][c2];
      ushort4 u0=s4[0], u1=s4[1], u2=s4[2], u3=s4[3];
      ushort4* d4 = (ushort4*)(dst0 + kt*64);
      d4[0]=u0; d4[1]=u1; d4[2]=u2; d4[3]=u3;
    }
    __builtin_amdgcn_wave_barrier();
    __syncthreads();   // stage(kt+1) complete; reads of cur done before overwrite at kt+2
  }
}

// ------- Kernel 2 (single pass): P = exp((QK^T + bias)/8) -> ws (unnormalized, over bias);
//         OUT = (P*V)/rowsum(P).  XCD swizzle: all 16 qt-blocks of a bh on one XCD (K/V L2-hot).
//         2 __syncthreads/tile: pt phase is wave-local (wave_barrier); PV before P-writeout.
__global__ __launch_bounds__(256) void k_attn(const float* __restrict__ Q,
                                              const float* __restrict__ K,
                                              const float* __restrict__ V,
                                              unsigned short* WS,
                                              float* __restrict__ OUT){
  __shared__ unsigned short kt_[64][68];
  __shared__ unsigned short bt[64][68];
  __shared__ unsigned short pt[64][68];
  __shared__ unsigned short vt[64][68];
  const int bid = blockIdx.x;
  const int bh = (bid & 7) + ((bid >> 7) << 3);   // bid = (bh&7) + 8*((bh>>3)*16 + qtIdx)
  const int qt = ((bid >> 3) & 15) * 64;
  const int tid = threadIdx.x;
  const int w = tid >> 6, l = tid & 63, lr = l & 15, lg = l >> 4;

  bf16x8 a0, a1;   // A rows q = qt+16w+lr
  {
    const float4* q4 = (const float4*)(Q + ((size_t)bh * Tt + qt + 16*w + lr) * Dh);
    a0 = pack8(q4[lg*2],     q4[lg*2 + 1]);
    a1 = pack8(q4[8 + lg*2], q4[8 + lg*2 + 1]);
  }
  const float* kb = K + (size_t)bh * Tt * Dh;
  const float* vb = V + (size_t)bh * Tt * Dh;
  unsigned short* wsb = WS + (size_t)bh * Tt * Tt;

  float lsum[4] = {0.f,0.f,0.f,0.f};
  f32x4 oacc[4];
#pragma unroll
  for (int c = 0; c < 4; ++c) oacc[c] = (f32x4){0.f,0.f,0.f,0.f};

  for (int kt = 0; kt < 16; ++kt){
    stage64x64(kb + (size_t)kt * 64 * Dh, kt_, tid);
    stage_rows(wsb + (size_t)qt * Tt + kt*64, Tt, bt, tid);
    stage64x64T4(vb + (size_t)kt * 64 * Dh, vt, tid);
    __syncthreads();
#pragma unroll
    for (int c = 0; c < 4; ++c){
      bf16x8 b0 = ldsfrag(kt_, c*16 + lr, lg*8);
      bf16x8 b1 = ldsfrag(kt_, c*16 + lr, lg*8 + 32);
      f32x4 z = {0.f,0.f,0.f,0.f};
      z = mfma16(a0, b0, z);
      z = mfma16(a1, b1, z);
      int kl = c*16 + lr;
#pragma unroll
      for (int j = 0; j < 4; ++j){
        float s = (z[j] + bf2f(bt[16*w + lg*4 + j][kl])) * SCALE;
        float p = __expf(s);
        lsum[j] += p;
        pt[16*w + lg*4 + j][kl] = f2bf(p);
      }
    }
    __builtin_amdgcn_wave_barrier();   // pt writers == readers (same wave rows)
    // PV first (MFMA issues immediately), then the independent P-writeout
    bf16x8 p0 = ldsfrag(pt, 16*w + lr, lg*8);
    bf16x8 p1 = ldsfrag(pt, 16*w + lr, lg*8 + 32);
#pragma unroll
    for (int c = 0; c < 4; ++c){
      bf16x8 v0 = ldsfrag(vt, c*16 + lr, lg*8);
      bf16x8 v1 = ldsfrag(vt, c*16 + lr, lg*8 + 32);
      oacc[c] = mfma16(p0, v0, oacc[c]);
      oacc[c] = mfma16(p1, v1, oacc[c]);
    }
    {
      int r = l >> 2, c2 = (l & 3) * 16;
      const ushort4* s4 = (const ushort4*)&pt[16*w + r][c2];
      ushort4 u0=s4[0], u1=s4[1], u2=s4[2], u3=s4[3];
      ushort4* d4 = (ushort4*)(wsb + (size_t)(qt + 16*w + r) * Tt + kt*64 + c2);
      d4[0]=u0; d4[1]=u1; d4[2]=u2; d4[3]=u3;
    }
    __syncthreads();   // all reads of kt_/bt/vt/pt done before next tile's staging
  }
  float rl[4];
#pragma unroll
  for (int j = 0; j < 4; ++j){
    float su = lsum[j];
    for (int o = 1; o < 16; o <<= 1) su += __shfl_xor(su, o, 64);
    rl[j] = 1.f / su;
  }
#pragma unroll
  for (int c = 0; c < 4; ++c)
#pragma unroll
    for (int j = 0; j < 4; ++j)
      OUT[((size_t)bh * Tt + qt + 16*w + lg*4 + j) * Dh + c*16 + lr] = oacc[c][j] * rl[j];
}

// ---------------- Kernel 3: OUT[bh,q,d] += (sum_k P[bh,q,k]*Ev[q,k,d]) / rowsum(P) ----------------
// P A-operand loaded directly (coalesced row-major); Ev staged via 4x4 block transpose, double-buffered.
__global__ __launch_bounds__(256) void k_aev(const unsigned short* __restrict__ WS,
                                             const float* __restrict__ EV,
                                             float* __restrict__ OUT){
  __shared__ unsigned short evt[2][64][68];
  __shared__ float sums[64];
  const int qi = blockIdx.x;
  const int tid = threadIdx.x;
  const int w = tid >> 6, l = tid & 63, lr = l & 15, lg = l >> 4;

  const unsigned short* arow = WS + (size_t)(16*w + lr) * Tt * Tt + (size_t)qi * Tt;
  const float* evq = EV + (size_t)qi * Tt * Dh;

  f32x4 acc[4];
#pragma unroll
  for (int c = 0; c < 4; ++c) acc[c] = (f32x4){0.f,0.f,0.f,0.f};
  float asum = 0.f;

  stage64x64T4(evq, evt[0], tid);
  __syncthreads();

  for (int kt = 0; kt < 16; ++kt){
    if (kt < 15) stage64x64T4(evq + (size_t)(kt+1) * 64 * Dh, evt[(kt+1)&1], tid);
    const unsigned short (*cur)[68] = evt[kt&1];
    bf16x8 a0 = *(const bf16x8*)(arow + kt*64 + lg*8);
    bf16x8 a1 = *(const bf16x8*)(arow + kt*64 + 32 + lg*8);
    asum += fragsum(a0) + fragsum(a1);
#pragma unroll
    for (int c = 0; c < 4; ++c){
      bf16x8 b0 = ldsfrag(cur, c*16 + lr, lg*8);
      bf16x8 b1 = ldsfrag(cur, c*16 + lr, lg*8 + 32);
      acc[c] = mfma16(a0, b0, acc[c]);
      acc[c] = mfma16(a1, b1, acc[c]);
    }
    __syncthreads();
  }
  asum += __shfl_xor(asum, 16, 64);
  asum += __shfl_xor(asum, 32, 64);
  if (lg == 0) sums[16*w + lr] = asum;   // wave-local broadcast
  __builtin_amdgcn_wave_barrier();

#pragma unroll
  for (int c = 0; c < 4; ++c)
#pragma unroll
    for (int j = 0; j < 4; ++j){
      int bh = 16*w + lg*4 + j;
      float rl = 1.f / sums[bh];
      size_t idx = ((size_t)bh * Tt + qi) * Dh + c*16 + lr;
      OUT[idx] += acc[c][j] * rl;
    }
}

extern "C" void kernel_launch(void* const* d_in, const int* in_sizes, int n_in,
                              void* d_out, int out_size, void* d_ws, size_t ws_size,
                              hipStream_t stream){
  const float* Q  = (const float*)d_in[0];
  const float* K  = (const float*)d_in[1];
  const float* V  = (const float*)d_in[2];
  const float* EK = (const float*)d_in[3];
  const float* EV = (const float*)d_in[4];
  float* OUT = (float*)d_out;
  unsigned short* WS = (unsigned short*)d_ws;

  if (ws_size < (size_t)64 * Tt * Tt * sizeof(unsigned short)) return;

  k_qek <<<dim3(1024), dim3(256), 0, stream>>>(Q, EK, WS);
  k_attn<<<dim3(1024), dim3(256), 0, stream>>>(Q, K, V, WS, OUT);
  k_aev <<<dim3(1024), dim3(256), 0, stream>>>(WS, EV, OUT);
}

// Round 10
// 255.513 us; speedup vs baseline: 1.2146x; 1.0510x over previous
//
#include <hip/hip_runtime.h>

#define Tt 1024
#define Dh 64
#define SCALE 0.125f

typedef __attribute__((ext_vector_type(4))) float f32x4;
typedef __attribute__((ext_vector_type(2))) float f32x2;
typedef __attribute__((ext_vector_type(8))) short bf16x8;

__device__ inline unsigned short f2bf(float x){
  __bf16 h = (__bf16)x;
  return __builtin_bit_cast(unsigned short, h);
}
__device__ inline float bf2f(unsigned short h){
  return __uint_as_float(((unsigned)h) << 16);
}
__device__ inline ushort4 pack4(float4 f){
  ushort4 u; u.x=f2bf(f.x); u.y=f2bf(f.y); u.z=f2bf(f.z); u.w=f2bf(f.w); return u;
}
__device__ inline bf16x8 pack8(float4 a, float4 b){
  bf16x8 r;
  r[0]=(short)f2bf(a.x); r[1]=(short)f2bf(a.y); r[2]=(short)f2bf(a.z); r[3]=(short)f2bf(a.w);
  r[4]=(short)f2bf(b.x); r[5]=(short)f2bf(b.y); r[6]=(short)f2bf(b.z); r[7]=(short)f2bf(b.w);
  return r;
}
__device__ inline f32x4 mfma16(bf16x8 a, bf16x8 b, f32x4 c){
  return __builtin_amdgcn_mfma_f32_16x16x32_bf16(a, b, c, 0, 0, 0);
}
// pack 4 bf16 (as ushort4) * 2^-5 -> 4 fp8 e4m3 in one dword
__device__ inline unsigned pk8(ushort4 u){
  float f0 = bf2f(u.x)*0.03125f, f1 = bf2f(u.y)*0.03125f;
  float f2_ = bf2f(u.z)*0.03125f, f3 = bf2f(u.w)*0.03125f;
  int r = __builtin_amdgcn_cvt_pk_fp8_f32(f0, f1, 0, false);
  r = __builtin_amdgcn_cvt_pk_fp8_f32(f2_, f3, r, true);
  return (unsigned)r;
}
// unpack 4 fp8 (one dword) -> 4 floats
__device__ inline void up8(unsigned v, float* f){
  f32x2 a = __builtin_amdgcn_cvt_pk_f32_fp8((int)v, false);
  f32x2 b = __builtin_amdgcn_cvt_pk_f32_fp8((int)v, true);
  f[0]=a[0]; f[1]=a[1]; f[2]=b[0]; f[3]=b[1];
}

// stage a [64][64] fp32 tile (row stride 64) -> bf16 LDS [64][68]
__device__ inline void stage64x64(const float* __restrict__ g, unsigned short (*lds)[68], int tid){
  int r = tid >> 2, c = (tid & 3) * 16;
  const float4* g4 = (const float4*)(g + (size_t)r * 64 + c);
  float4 f0 = g4[0], f1 = g4[1], f2_ = g4[2], f3 = g4[3];
  ushort4* d4 = (ushort4*)&lds[r][c];
  d4[0]=pack4(f0); d4[1]=pack4(f1); d4[2]=pack4(f2_); d4[3]=pack4(f3);
}
// stage a [64 k][64 d] fp32 tile TRANSPOSED -> lds[d][k] bf16, via 4x4 register-block transpose.
__device__ inline void stage64x64T4(const float* __restrict__ g, unsigned short (*lds)[68], int tid){
  const int kb = (tid >> 4) * 4, db = (tid & 15) * 4;
  float fv[4][4];
#pragma unroll
  for (int j = 0; j < 4; ++j){
    float4 f = *(const float4*)(g + (size_t)(kb + j) * 64 + db);
    fv[j][0]=f.x; fv[j][1]=f.y; fv[j][2]=f.z; fv[j][3]=f.w;
  }
#pragma unroll
  for (int i = 0; i < 4; ++i){
    ushort4 u;
    u.x=f2bf(fv[0][i]); u.y=f2bf(fv[1][i]); u.z=f2bf(fv[2][i]); u.w=f2bf(fv[3][i]);
    *(ushort4*)&lds[db + i][kb] = u;
  }
}
// stage 64 rows x 64 ushorts from global (row stride in ushorts) -> LDS [64][68]
__device__ inline void stage_rows(const unsigned short* __restrict__ g, size_t rowstride,
                                  unsigned short (*lds)[68], int tid){
  int r = tid >> 2, c = (tid & 3) * 16;
  const ushort4* s4 = (const ushort4*)(g + (size_t)r * rowstride + c);
  ushort4 u0=s4[0], u1=s4[1], u2=s4[2], u3=s4[3];
  ushort4* d4 = (ushort4*)&lds[r][c];
  d4[0]=u0; d4[1]=u1; d4[2]=u2; d4[3]=u3;
}
// read 8 consecutive bf16 from lds[row][col..col+7] (col multiple of 8)
__device__ inline bf16x8 ldsfrag(const unsigned short (*lds)[68], int row, int col){
  const ushort4* p = (const ushort4*)&lds[row][col];
  ushort4 u0 = p[0], u1 = p[1];
  bf16x8 r;
  r[0]=(short)u0.x; r[1]=(short)u0.y; r[2]=(short)u0.z; r[3]=(short)u0.w;
  r[4]=(short)u1.x; r[5]=(short)u1.y; r[6]=(short)u1.z; r[7]=(short)u1.w;
  return r;
}

// ---------------- Kernel 1: bias[bh][q][k] = sum_d Q[bh,q,d] * Ek[q,k,d]  (bf16 out) ----------------
__global__ __launch_bounds__(256) void k_qek(const float* __restrict__ Q,
                                             const float* __restrict__ EK,
                                             unsigned short* __restrict__ BIAS){
  __shared__ unsigned short ek[2][64][68];
  __shared__ unsigned short ot[4][16][68];
  const int qi = blockIdx.x;
  const int tid = threadIdx.x;
  const int w = tid >> 6, l = tid & 63, lr = l & 15, lg = l >> 4;

  bf16x8 a0, a1;   // A rows bh = 16w+lr, k-dim d = lg*8+i (+32)
  {
    const float4* q4 = (const float4*)(Q + ((size_t)(16*w + lr) * Tt + qi) * Dh);
    a0 = pack8(q4[lg*2],     q4[lg*2 + 1]);
    a1 = pack8(q4[8 + lg*2], q4[8 + lg*2 + 1]);
  }
  const float* ekq = EK + (size_t)qi * Tt * Dh;
  const int r = l >> 2, c2 = (l & 3) * 16;
  unsigned short* dst0 = BIAS + (size_t)(16*w + r) * Tt * Tt + (size_t)qi * Tt + c2;

  stage64x64(ekq, ek[0], tid);
  __syncthreads();

  for (int kt = 0; kt < 16; ++kt){
    if (kt < 15) stage64x64(ekq + (size_t)(kt+1) * 64 * Dh, ek[(kt+1)&1], tid);
    const unsigned short (*cur)[68] = ek[kt&1];
    f32x4 acc[4];
#pragma unroll
    for (int c = 0; c < 4; ++c){
      bf16x8 b0 = ldsfrag(cur, c*16 + lr, lg*8);
      bf16x8 b1 = ldsfrag(cur, c*16 + lr, lg*8 + 32);
      f32x4 z = {0.f,0.f,0.f,0.f};
      z = mfma16(a0, b0, z);
      z = mfma16(a1, b1, z);
      acc[c] = z;
    }
#pragma unroll
    for (int c = 0; c < 4; ++c)
#pragma unroll
      for (int j = 0; j < 4; ++j)
        ot[w][lg*4 + j][c*16 + lr] = f2bf(acc[c][j]);
    __builtin_amdgcn_wave_barrier();   // wave-local bounce: rows [16w,16w+16) only
    {
      const ushort4* s4 = (const ushort4*)&ot[w][r][c2];
      ushort4 u0=s4[0], u1=s4[1], u2=s4[2], u3=s4[3];
      ushort4* d4 = (ushort4*)(dst0 + kt*64);
      d4[0]=u0; d4[1]=u1; d4[2]=u2; d4[3]=u3;
    }
    __builtin_amdgcn_wave_barrier();
    __syncthreads();
  }
}

// ------- Kernel 2: P = exp((QK^T + bias)/8); out1 = (P*V)/rowsum(P) (bf16 path, unchanged);
//         P also stored as fp8 e4m3 scaled by 2^-5 (exact shift) for k_aev. ----
__global__ __launch_bounds__(256) void k_attn(const float* __restrict__ Q,
                                              const float* __restrict__ K,
                                              const float* __restrict__ V,
                                              const unsigned short* __restrict__ BIAS,
                                              unsigned char* __restrict__ P8,
                                              float* __restrict__ OUT){
  __shared__ unsigned short kt_[64][68];
  __shared__ unsigned short bt[64][68];
  __shared__ unsigned short pt[64][68];
  __shared__ unsigned short vt[64][68];
  const int bid = blockIdx.x;
  const int bh = (bid & 7) + ((bid >> 7) << 3);   // bid = (bh&7) + 8*((bh>>3)*16 + qtIdx)
  const int qt = ((bid >> 3) & 15) * 64;
  const int tid = threadIdx.x;
  const int w = tid >> 6, l = tid & 63, lr = l & 15, lg = l >> 4;

  bf16x8 a0, a1;   // A rows q = qt+16w+lr
  {
    const float4* q4 = (const float4*)(Q + ((size_t)bh * Tt + qt + 16*w + lr) * Dh);
    a0 = pack8(q4[lg*2],     q4[lg*2 + 1]);
    a1 = pack8(q4[8 + lg*2], q4[8 + lg*2 + 1]);
  }
  const float* kb = K + (size_t)bh * Tt * Dh;
  const float* vb = V + (size_t)bh * Tt * Dh;
  const unsigned short* bsb = BIAS + (size_t)bh * Tt * Tt;
  unsigned char* p8b = P8 + (size_t)bh * Tt * Tt;

  float lsum[4] = {0.f,0.f,0.f,0.f};
  f32x4 oacc[4];
#pragma unroll
  for (int c = 0; c < 4; ++c) oacc[c] = (f32x4){0.f,0.f,0.f,0.f};

  for (int kt = 0; kt < 16; ++kt){
    stage64x64(kb + (size_t)kt * 64 * Dh, kt_, tid);
    stage_rows(bsb + (size_t)qt * Tt + kt*64, Tt, bt, tid);
    stage64x64T4(vb + (size_t)kt * 64 * Dh, vt, tid);
    __syncthreads();
#pragma unroll
    for (int c = 0; c < 4; ++c){
      bf16x8 b0 = ldsfrag(kt_, c*16 + lr, lg*8);
      bf16x8 b1 = ldsfrag(kt_, c*16 + lr, lg*8 + 32);
      f32x4 z = {0.f,0.f,0.f,0.f};
      z = mfma16(a0, b0, z);
      z = mfma16(a1, b1, z);
      int kl = c*16 + lr;
#pragma unroll
      for (int j = 0; j < 4; ++j){
        float s = (z[j] + bf2f(bt[16*w + lg*4 + j][kl])) * SCALE;
        float p = __expf(s);
        lsum[j] += p;
        pt[16*w + lg*4 + j][kl] = f2bf(p);
      }
    }
    __builtin_amdgcn_wave_barrier();   // pt writers == readers (same wave rows)
    // PV first (MFMA issues immediately), then the independent P8 writeout
    bf16x8 p0 = ldsfrag(pt, 16*w + lr, lg*8);
    bf16x8 p1 = ldsfrag(pt, 16*w + lr, lg*8 + 32);
#pragma unroll
    for (int c = 0; c < 4; ++c){
      bf16x8 v0 = ldsfrag(vt, c*16 + lr, lg*8);
      bf16x8 v1 = ldsfrag(vt, c*16 + lr, lg*8 + 32);
      oacc[c] = mfma16(p0, v0, oacc[c]);
      oacc[c] = mfma16(p1, v1, oacc[c]);
    }
    {
      int r = l >> 2, cq = (l & 3);
      const ushort4* s4 = (const ushort4*)&pt[16*w + r][cq*16];
      ushort4 u0=s4[0], u1=s4[1], u2=s4[2], u3=s4[3];
      uint4 o;
      o.x = pk8(u0); o.y = pk8(u1); o.z = pk8(u2); o.w = pk8(u3);
      *(uint4*)(p8b + ((size_t)(qt + 16*w + r) << 10) + kt*64 + cq*16) = o;
    }
    __syncthreads();
  }
  float rl[4];
#pragma unroll
  for (int j = 0; j < 4; ++j){
    float su = lsum[j];
    for (int o = 1; o < 16; o <<= 1) su += __shfl_xor(su, o, 64);
    rl[j] = 1.f / su;
  }
#pragma unroll
  for (int c = 0; c < 4; ++c)
#pragma unroll
    for (int j = 0; j < 4; ++j)
      OUT[((size_t)bh * Tt + qt + 16*w + lg*4 + j) * Dh + c*16 + lr] = oacc[c][j] * rl[j];
}

// ---------------- Kernel 3: OUT[bh,q,d] += (sum_k P*Ev)/rowsum(P), P from fp8 ----------------
// Scale 2^-5 cancels in num/denom (row sum computed from the same fp8 values).
__global__ __launch_bounds__(256) void k_aev(const unsigned char* __restrict__ P8,
                                             const float* __restrict__ EV,
                                             float* __restrict__ OUT){
  __shared__ unsigned short evt[2][64][68];
  __shared__ float sums[64];
  const int qi = blockIdx.x;
  const int tid = threadIdx.x;
  const int w = tid >> 6, l = tid & 63, lr = l & 15, lg = l >> 4;

  const unsigned char* arow = P8 + (size_t)(16*w + lr) * Tt * Tt + (size_t)qi * Tt;
  const float* evq = EV + (size_t)qi * Tt * Dh;

  f32x4 acc[4];
#pragma unroll
  for (int c = 0; c < 4; ++c) acc[c] = (f32x4){0.f,0.f,0.f,0.f};
  float asum = 0.f;

  stage64x64T4(evq, evt[0], tid);
  __syncthreads();

  for (int kt = 0; kt < 16; ++kt){
    if (kt < 15) stage64x64T4(evq + (size_t)(kt+1) * 64 * Dh, evt[(kt+1)&1], tid);
    const unsigned short (*cur)[68] = evt[kt&1];
    uint2 ua = *(const uint2*)(arow + kt*64 + lg*8);
    uint2 ub = *(const uint2*)(arow + kt*64 + 32 + lg*8);
    float fa[8], fb[8];
    up8(ua.x, fa); up8(ua.y, fa+4);
    up8(ub.x, fb); up8(ub.y, fb+4);
    bf16x8 a0, a1;
#pragma unroll
    for (int i = 0; i < 8; ++i){
      asum += fa[i] + fb[i];
      a0[i] = (short)f2bf(fa[i]);
      a1[i] = (short)f2bf(fb[i]);
    }
#pragma unroll
    for (int c = 0; c < 4; ++c){
      bf16x8 b0 = ldsfrag(cur, c*16 + lr, lg*8);
      bf16x8 b1 = ldsfrag(cur, c*16 + lr, lg*8 + 32);
      acc[c] = mfma16(a0, b0, acc[c]);
      acc[c] = mfma16(a1, b1, acc[c]);
    }
    __syncthreads();
  }
  asum += __shfl_xor(asum, 16, 64);
  asum += __shfl_xor(asum, 32, 64);
  if (lg == 0) sums[16*w + lr] = asum;   // wave-local broadcast
  __builtin_amdgcn_wave_barrier();

#pragma unroll
  for (int c = 0; c < 4; ++c)
#pragma unroll
    for (int j = 0; j < 4; ++j){
      int bh = 16*w + lg*4 + j;
      float rl = 1.f / sums[bh];
      size_t idx = ((size_t)bh * Tt + qi) * Dh + c*16 + lr;
      OUT[idx] += acc[c][j] * rl;
    }
}

extern "C" void kernel_launch(void* const* d_in, const int* in_sizes, int n_in,
                              void* d_out, int out_size, void* d_ws, size_t ws_size,
                              hipStream_t stream){
  const float* Q  = (const float*)d_in[0];
  const float* K  = (const float*)d_in[1];
  const float* V  = (const float*)d_in[2];
  const float* EK = (const float*)d_in[3];
  const float* EV = (const float*)d_in[4];
  float* OUT = (float*)d_out;
  unsigned short* BIAS = (unsigned short*)d_ws;                        // 128 MiB bf16
  unsigned char*  P8   = (unsigned char*)(BIAS + (size_t)64*Tt*Tt);    // 64 MiB fp8

  if (ws_size < (size_t)64*Tt*Tt*sizeof(unsigned short) + (size_t)64*Tt*Tt) return;

  k_qek <<<dim3(1024), dim3(256), 0, stream>>>(Q, EK, BIAS);
  k_attn<<<dim3(1024), dim3(256), 0, stream>>>(Q, K, V, BIAS, P8, OUT);
  k_aev <<<dim3(1024), dim3(256), 0, stream>>>(P8, EV, OUT);
}